// Round 13
// baseline (1265.632 us; speedup 1.0000x reference)
//
#include <hip/hip_runtime.h>
#include <hip/hip_bf16.h>
#include <math.h>

typedef __hip_bfloat16 bf16;

#define N_NODES 50000
#define N_EDGES 800000
#define IN_DIM 50
#define HIDDEN 256
#define NCLS 121
#define PSTR 128  // padded stride for p rows (128 bf16 = 256 B)

// ---- workspace layout (4-byte units) ----
// degi : int   [0, +50000)
// off  : int   [50048, +50001)
// cur  : int   [100112, +50000)
// csr  : int   [150160, +800000)
// h    : float [950272, +12800000)                  -> ends 13750272
// pb   : bf16  [13750272, +3200000 floats)          -> ends 16950272  (50000*128 bf16)
// xb   : bf16  [16950272, +1250000 floats)          -> ends 18200272  (50000*50 bf16 = 5 MB)
// wT   : float [18200320, +131328)                  -> ends 18331648 (73.3 MB total)
#define OFF_OFF  50048
#define OFF_CUR  100112
#define OFF_CSR  150160
#define OFF_H    950272
#define OFF_PB   13750272
#define OFF_XB   16950272
#define OFF_WT   18200320   // FIXED: was 17575424, which overlapped xb
// within wT (float units):
#define WT_W1L 0
#define WT_W1R 12800
#define WT_WL1 25600
#define WT_W2L 38400
#define WT_W2R 69376
#define WT_WL2 100352

__device__ __forceinline__ int clampi(int v, int hi) {
    return v < 0 ? 0 : (v >= hi ? hi - 1 : v);
}

// ---------------- x -> bf16 copy ----------------
__global__ __launch_bounds__(256) void convx_r13(const float* __restrict__ x,
                                                 bf16* __restrict__ xb) {
    int i = blockIdx.x * 256 + threadIdx.x;
    if (i < N_NODES * IN_DIM) xb[i] = __float2bfloat16(x[i]);
}

// ---------------- weight transposes ----------------
// layer1 weights: [IN_DIM][HIDDEN] -> [HIDDEN][IN_DIM]
__global__ __launch_bounds__(256) void tr1_r13(const float* __restrict__ a,
                                               const float* __restrict__ b,
                                               const float* __restrict__ c,
                                               float* __restrict__ wt) {
    int i = blockIdx.x * 256 + threadIdx.x;
    if (i >= IN_DIM * HIDDEN) return;
    int j = i / IN_DIM, f = i % IN_DIM;
    wt[WT_W1L + i] = a[f * HIDDEN + j];
    wt[WT_W1R + i] = b[f * HIDDEN + j];
    wt[WT_WL1 + i] = c[f * HIDDEN + j];
}

// layer2 weights: [HIDDEN][NCLS] -> [NCLS][HIDDEN]
__global__ __launch_bounds__(256) void tr2_r13(const float* __restrict__ a,
                                               const float* __restrict__ b,
                                               const float* __restrict__ c,
                                               float* __restrict__ wt) {
    int i = blockIdx.x * 256 + threadIdx.x;
    if (i >= NCLS * HIDDEN) return;
    int j = i / HIDDEN, k = i % HIDDEN;
    wt[WT_W2L + i] = a[k * NCLS + j];
    wt[WT_W2R + i] = b[k * NCLS + j];
    wt[WT_WL2 + i] = c[k * NCLS + j];
}

// ---------------- CSR build ----------------
__global__ __launch_bounds__(256) void degcount_r13(const int* __restrict__ dst,
                                                    int* __restrict__ degi) {
    int e = blockIdx.x * 256 + threadIdx.x;
    if (e < N_EDGES) atomicAdd(&degi[clampi(dst[e], N_NODES)], 1);
}

__global__ __launch_bounds__(256) void scan_r13(const int* __restrict__ degi,
                                                int* __restrict__ off,
                                                int* __restrict__ cur) {
    __shared__ int part[256];
    const int CH = (N_NODES + 255) / 256;
    int t = threadIdx.x;
    int begin = t * CH;
    int end = begin + CH < N_NODES ? begin + CH : N_NODES;
    int s = 0;
    for (int i = begin; i < end; ++i) s += degi[i];
    part[t] = s;
    __syncthreads();
    for (int d = 1; d < 256; d <<= 1) {
        int u = (t >= d) ? part[t - d] : 0;
        __syncthreads();
        part[t] += u;
        __syncthreads();
    }
    int run = part[t] - s;
    for (int i = begin; i < end; ++i) {
        off[i] = run;
        cur[i] = run;
        run += degi[i];
    }
    if (end == N_NODES) off[N_NODES] = run;
}

__global__ __launch_bounds__(256) void csrfill_r13(const int* __restrict__ src,
                                                   const int* __restrict__ dst,
                                                   int* __restrict__ cur,
                                                   int* __restrict__ csr) {
    int e = blockIdx.x * 256 + threadIdx.x;
    if (e >= N_EDGES) return;
    int d = clampi(dst[e], N_NODES);
    int pos = atomicAdd(&cur[d], 1);
    csr[pos] = clampi(src[e], N_NODES);
}

// ---------------- layer 1: 8 nodes, 256 thr, float2 dense loop --------------
__global__ __launch_bounds__(256, 4) void layer1_r13(
    const float* __restrict__ x, const bf16* __restrict__ xb,
    const int* __restrict__ off, const int* __restrict__ csr,
    const int* __restrict__ degi, const float* __restrict__ wt,
    const float* __restrict__ b1, const float* __restrict__ bl1,
    float* __restrict__ h) {
    __shared__ float xs[8][IN_DIM];
    __shared__ float ms[8][IN_DIM];
    __shared__ float red[8][HIDDEN];
    __shared__ float rdeg[8];

    int base = blockIdx.x * 8;
    int tid = threadIdx.x;
    int wave = tid >> 6, lane = tid & 63;

    if (tid < 8) rdeg[tid] = 1.0f / fmaxf((float)degi[base + tid], 1.0f);
    for (int idx = tid; idx < 8 * IN_DIM; idx += 256) {
        int n = idx / IN_DIM, f = idx % IN_DIM;
        xs[n][f] = x[(base + n) * IN_DIM + f];  // root term: exact fp32
    }
    // bf16 gather-aggregate, 4-way MLP
    for (int r = 0; r < 2; ++r) {
        int n = wave * 2 + r;
        int node = base + n;
        int e0 = off[node], e1 = off[node + 1];
        float a0 = 0, a1 = 0, a2 = 0, a3 = 0;
        int e = e0;
        for (; e + 4 <= e1; e += 4) {
            int s0 = csr[e], s1 = csr[e + 1], s2 = csr[e + 2], s3 = csr[e + 3];
            if (lane < IN_DIM) {
                a0 += __bfloat162float(xb[s0 * IN_DIM + lane]);
                a1 += __bfloat162float(xb[s1 * IN_DIM + lane]);
                a2 += __bfloat162float(xb[s2 * IN_DIM + lane]);
                a3 += __bfloat162float(xb[s3 * IN_DIM + lane]);
            }
        }
        for (; e < e1; ++e)
            if (lane < IN_DIM) a0 += __bfloat162float(xb[csr[e] * IN_DIM + lane]);
        if (lane < IN_DIM) ms[n][lane] = (a0 + a1) + (a2 + a3);
    }
    __syncthreads();

    int j = tid;  // hidden column
    const float* wa = wt + WT_W1L + j * IN_DIM;
    const float* wb = wt + WT_W1R + j * IN_DIM;
    const float* wc = wt + WT_WL1 + j * IN_DIM;
    float accA[8] = {0}, accB[8] = {0}, accC[8] = {0};
    for (int f = 0; f < IN_DIM; f += 2) {  // 50 = 25 pairs exactly
        float2 wa2 = *(const float2*)&wa[f];
        float2 wb2 = *(const float2*)&wb[f];
        float2 wc2 = *(const float2*)&wc[f];
#pragma unroll
        for (int n = 0; n < 8; ++n) {
            float2 mv = *(const float2*)&ms[n][f];
            float2 xv = *(const float2*)&xs[n][f];
            accA[n] += mv.x * wa2.x + mv.y * wa2.y;
            accB[n] += xv.x * wb2.x + xv.y * wb2.y;
            accC[n] += xv.x * wc2.x + xv.y * wc2.y;
        }
    }
    float bj = b1[j];
    float blj = bl1[j];
    float out1[8];
#pragma unroll
    for (int n = 0; n < 8; ++n) {
        out1[n] = accA[n] * rdeg[n] + bj + accB[n];
        red[n][j] = out1[n] * out1[n];
    }
    __syncthreads();
    for (int stride = 128; stride > 0; stride >>= 1) {
        if (j < stride) {
#pragma unroll
            for (int n = 0; n < 8; ++n) red[n][j] += red[n][j + stride];
        }
        __syncthreads();
    }
#pragma unroll
    for (int n = 0; n < 8; ++n) {
        float rn = 1.0f / fmaxf(sqrtf(red[n][0]), 1e-12f);
        float z = out1[n] * rn + accC[n] + blj;
        h[(base + n) * HIDDEN + j] = z > 0.0f ? z : expm1f(z);
    }
}

// ---------------- p = h @ w2_l (bf16 out), float2 dense loop ----------------
__global__ __launch_bounds__(128, 4) void project2_r13(
    const float* __restrict__ h, const float* __restrict__ wt,
    bf16* __restrict__ pb) {
    __shared__ float hs[8][HIDDEN];
    int base = blockIdx.x * 8;
    int tid = threadIdx.x;
    for (int idx = tid; idx < 8 * HIDDEN; idx += 128) {
        int n = idx >> 8, k = idx & 255;
        hs[n][k] = h[(base + n) * HIDDEN + k];
    }
    __syncthreads();
    int j = tid;
    if (j >= NCLS) return;
    const float* w = wt + WT_W2L + j * HIDDEN;
    float acc[8] = {0};
    for (int k = 0; k < HIDDEN; k += 2) {
        float2 w2 = *(const float2*)&w[k];
#pragma unroll
        for (int n = 0; n < 8; ++n) {
            float2 hv = *(const float2*)&hs[n][k];
            acc[n] += hv.x * w2.x + hv.y * w2.y;
        }
    }
#pragma unroll
    for (int n = 0; n < 8; ++n)
        pb[(base + n) * PSTR + j] = __float2bfloat16(acc[n]);
}

// ---------------- layer 2 final: 8 nodes, 128 thr, float2 dense loop --------
__global__ __launch_bounds__(128, 4) void layer2_r13(
    const float* __restrict__ h, const bf16* __restrict__ pb,
    const int* __restrict__ off, const int* __restrict__ csr,
    const int* __restrict__ degi, const float* __restrict__ wt,
    const float* __restrict__ b2, const float* __restrict__ bl2,
    float* __restrict__ out) {
    __shared__ float hs[8][HIDDEN];
    __shared__ float mp[8][NCLS];
    __shared__ float red[8][128];
    __shared__ float rdeg[8];

    int base = blockIdx.x * 8;
    int tid = threadIdx.x;
    if (tid < 8) rdeg[tid] = 1.0f / fmaxf((float)degi[base + tid], 1.0f);
    for (int idx = tid; idx < 8 * HIDDEN; idx += 128) {
        int n = idx >> 8, k = idx & 255;
        hs[n][k] = h[(base + n) * HIDDEN + k];
    }
    // bf16 gather-aggregate of p, 4-way MLP
    for (int n = 0; n < 8; ++n) {
        int node = base + n;
        int e0 = off[node], e1 = off[node + 1];
        if (tid < NCLS) {
            float a0 = 0, a1 = 0, a2 = 0, a3 = 0;
            int e = e0;
            for (; e + 4 <= e1; e += 4) {
                int s0 = csr[e], s1 = csr[e + 1];
                int s2 = csr[e + 2], s3 = csr[e + 3];
                a0 += __bfloat162float(pb[s0 * PSTR + tid]);
                a1 += __bfloat162float(pb[s1 * PSTR + tid]);
                a2 += __bfloat162float(pb[s2 * PSTR + tid]);
                a3 += __bfloat162float(pb[s3 * PSTR + tid]);
            }
            for (; e < e1; ++e) a0 += __bfloat162float(pb[csr[e] * PSTR + tid]);
            mp[n][tid] = (a0 + a1) + (a2 + a3);
        }
    }
    __syncthreads();

    int j = tid;
    float accB[8] = {0}, accC[8] = {0};
    if (j < NCLS) {
        const float* wb = wt + WT_W2R + j * HIDDEN;
        const float* wc = wt + WT_WL2 + j * HIDDEN;
        for (int k = 0; k < HIDDEN; k += 2) {
            float2 wb2 = *(const float2*)&wb[k];
            float2 wc2 = *(const float2*)&wc[k];
#pragma unroll
            for (int n = 0; n < 8; ++n) {
                float2 hv = *(const float2*)&hs[n][k];
                accB[n] += hv.x * wb2.x + hv.y * wb2.y;
                accC[n] += hv.x * wc2.x + hv.y * wc2.y;
            }
        }
    }
    float bj = (j < NCLS) ? b2[j] : 0.0f;
    float blj = (j < NCLS) ? bl2[j] : 0.0f;
    float out2[8];
#pragma unroll
    for (int n = 0; n < 8; ++n) {
        out2[n] = (j < NCLS) ? (mp[n][j] * rdeg[n] + bj + accB[n]) : 0.0f;
        red[n][j] = out2[n] * out2[n];
    }
    __syncthreads();
    for (int stride = 64; stride > 0; stride >>= 1) {
        if (j < stride) {
#pragma unroll
            for (int n = 0; n < 8; ++n) red[n][j] += red[n][j + stride];
        }
        __syncthreads();
    }
    if (j < NCLS) {
#pragma unroll
        for (int n = 0; n < 8; ++n) {
            float rn = 1.0f / fmaxf(sqrtf(red[n][0]), 1e-12f);
            out[(base + n) * NCLS + j] = out2[n] * rn + accC[n] + blj;
        }
    }
}

extern "C" void kernel_launch(void* const* d_in, const int* in_sizes, int n_in,
                              void* d_out, int out_size, void* d_ws, size_t ws_size,
                              hipStream_t stream) {
    const float* x   = (const float*)d_in[0];
    const int*   ei  = (const int*)d_in[1];
    const float* w1l = (const float*)d_in[2];
    const float* b1  = (const float*)d_in[3];
    const float* w1r = (const float*)d_in[4];
    const float* wl1 = (const float*)d_in[5];
    const float* bl1 = (const float*)d_in[6];
    const float* w2l = (const float*)d_in[7];
    const float* b2  = (const float*)d_in[8];
    const float* w2r = (const float*)d_in[9];
    const float* wl2 = (const float*)d_in[10];
    const float* bl2 = (const float*)d_in[11];
    float* out = (float*)d_out;

    const int* src = ei;
    const int* dst = ei + N_EDGES;

    int*   wsI  = (int*)d_ws;
    float* wsF  = (float*)d_ws;
    int*   degi = wsI;
    int*   off  = wsI + OFF_OFF;
    int*   cur  = wsI + OFF_CUR;
    int*   csr  = wsI + OFF_CSR;
    float* h    = wsF + OFF_H;
    bf16*  pb   = (bf16*)(wsF + OFF_PB);
    bf16*  xb   = (bf16*)(wsF + OFF_XB);
    float* wt   = wsF + OFF_WT;

    hipMemsetAsync(degi, 0, (size_t)N_NODES * sizeof(int), stream);

    convx_r13<<<(N_NODES * IN_DIM + 255) / 256, 256, 0, stream>>>(x, xb);
    tr1_r13<<<(IN_DIM * HIDDEN + 255) / 256, 256, 0, stream>>>(w1l, w1r, wl1, wt);
    tr2_r13<<<(NCLS * HIDDEN + 255) / 256, 256, 0, stream>>>(w2l, w2r, wl2, wt);
    degcount_r13<<<(N_EDGES + 255) / 256, 256, 0, stream>>>(dst, degi);
    scan_r13<<<1, 256, 0, stream>>>(degi, off, cur);
    csrfill_r13<<<(N_EDGES + 255) / 256, 256, 0, stream>>>(src, dst, cur, csr);

    layer1_r13<<<N_NODES / 8, 256, 0, stream>>>(x, xb, off, csr, degi, wt,
                                                b1, bl1, h);
    project2_r13<<<N_NODES / 8, 128, 0, stream>>>(h, wt, pb);
    layer2_r13<<<N_NODES / 8, 128, 0, stream>>>(h, pb, off, csr, degi, wt,
                                                b2, bl2, out);
}

// Round 14
// 689.030 us; speedup vs baseline: 1.8368x; 1.8368x over previous
//
#include <hip/hip_runtime.h>
#include <hip/hip_bf16.h>
#include <math.h>

typedef __hip_bfloat16 bf16;

#define N_NODES 50000
#define N_EDGES 800000
#define IN_DIM 50
#define HIDDEN 256
#define NCLS 121
#define PSTR 128  // padded stride for p rows (128 bf16 = 256 B)

// ---- workspace layout (4-byte units) ----
// degi : int   [0, +50000)
// off  : int   [50048, +50001)
// cur  : int   [100112, +50000)
// csr  : int   [150160, +800000)
// h    : float [950272, +12800000)        -> ends 13750272
// pb   : bf16  [13750272, +1600000 fl)    -> ends 15350272 (50000*128 bf16)
// xb   : bf16  [15350272, +1250000 fl)    -> ends 16600272 (50000*50 bf16)
// total 66.4 MB (ws >= 103 MB verified)
#define OFF_OFF  50048
#define OFF_CUR  100112
#define OFF_CSR  150160
#define OFF_H    950272
#define OFF_PB   13750272
#define OFF_XB   15350272

__device__ __forceinline__ int clampi(int v, int hi) {
    return v < 0 ? 0 : (v >= hi ? hi - 1 : v);
}

// ---------------- x -> bf16 copy ----------------
__global__ __launch_bounds__(256) void convx_r14(const float* __restrict__ x,
                                                 bf16* __restrict__ xb) {
    int i = blockIdx.x * 256 + threadIdx.x;
    if (i < N_NODES * IN_DIM) xb[i] = __float2bfloat16(x[i]);
}

// ---------------- CSR build ----------------
__global__ __launch_bounds__(256) void degcount_r14(const int* __restrict__ dst,
                                                    int* __restrict__ degi) {
    int e = blockIdx.x * 256 + threadIdx.x;
    if (e < N_EDGES) atomicAdd(&degi[clampi(dst[e], N_NODES)], 1);
}

__global__ __launch_bounds__(256) void scan_r14(const int* __restrict__ degi,
                                                int* __restrict__ off,
                                                int* __restrict__ cur) {
    __shared__ int part[256];
    const int CH = (N_NODES + 255) / 256;
    int t = threadIdx.x;
    int begin = t * CH;
    int end = begin + CH < N_NODES ? begin + CH : N_NODES;
    int s = 0;
    for (int i = begin; i < end; ++i) s += degi[i];
    part[t] = s;
    __syncthreads();
    for (int d = 1; d < 256; d <<= 1) {
        int u = (t >= d) ? part[t - d] : 0;
        __syncthreads();
        part[t] += u;
        __syncthreads();
    }
    int run = part[t] - s;
    for (int i = begin; i < end; ++i) {
        off[i] = run;
        cur[i] = run;
        run += degi[i];
    }
    if (end == N_NODES) off[N_NODES] = run;
}

__global__ __launch_bounds__(256) void csrfill_r14(const int* __restrict__ src,
                                                   const int* __restrict__ dst,
                                                   int* __restrict__ cur,
                                                   int* __restrict__ csr) {
    int e = blockIdx.x * 256 + threadIdx.x;
    if (e >= N_EDGES) return;
    int d = clampi(dst[e], N_NODES);
    int pos = atomicAdd(&cur[d], 1);
    csr[pos] = clampi(src[e], N_NODES);
}

// ---------------- layer 1: 8 nodes, 256 thr, float2 LDS dense loop ----------
__global__ __launch_bounds__(256) void layer1_r14(
    const float* __restrict__ x, const bf16* __restrict__ xb,
    const int* __restrict__ off, const int* __restrict__ csr,
    const int* __restrict__ degi,
    const float* __restrict__ w1l, const float* __restrict__ b1,
    const float* __restrict__ w1r, const float* __restrict__ wl1,
    const float* __restrict__ bl1, float* __restrict__ h) {
    __shared__ float xs[8][IN_DIM];
    __shared__ float ms[8][IN_DIM];
    __shared__ float red[8][HIDDEN];
    __shared__ float rdeg[8];

    int base = blockIdx.x * 8;
    int tid = threadIdx.x;
    int wave = tid >> 6, lane = tid & 63;

    if (tid < 8) rdeg[tid] = 1.0f / fmaxf((float)degi[base + tid], 1.0f);
    for (int idx = tid; idx < 8 * IN_DIM; idx += 256) {
        int n = idx / IN_DIM, f = idx % IN_DIM;
        xs[n][f] = x[(base + n) * IN_DIM + f];  // root term: exact fp32
    }
    // bf16 gather-aggregate, 4-way MLP
    for (int r = 0; r < 2; ++r) {
        int n = wave * 2 + r;
        int node = base + n;
        int e0 = off[node], e1 = off[node + 1];
        float a0 = 0, a1 = 0, a2 = 0, a3 = 0;
        int e = e0;
        for (; e + 4 <= e1; e += 4) {
            int s0 = csr[e], s1 = csr[e + 1], s2 = csr[e + 2], s3 = csr[e + 3];
            if (lane < IN_DIM) {
                a0 += __bfloat162float(xb[s0 * IN_DIM + lane]);
                a1 += __bfloat162float(xb[s1 * IN_DIM + lane]);
                a2 += __bfloat162float(xb[s2 * IN_DIM + lane]);
                a3 += __bfloat162float(xb[s3 * IN_DIM + lane]);
            }
        }
        for (; e < e1; ++e)
            if (lane < IN_DIM) a0 += __bfloat162float(xb[csr[e] * IN_DIM + lane]);
        if (lane < IN_DIM) ms[n][lane] = (a0 + a1) + (a2 + a3);
    }
    __syncthreads();

    int j = tid;  // hidden column (coalesced weight reads: consecutive lanes)
    float accA[8] = {0}, accB[8] = {0}, accC[8] = {0};
    for (int f = 0; f < IN_DIM; f += 2) {  // 50 = 25 pairs exactly
        float wa0 = w1l[f * HIDDEN + j], wa1 = w1l[(f + 1) * HIDDEN + j];
        float wb0 = w1r[f * HIDDEN + j], wb1 = w1r[(f + 1) * HIDDEN + j];
        float wc0 = wl1[f * HIDDEN + j], wc1 = wl1[(f + 1) * HIDDEN + j];
#pragma unroll
        for (int n = 0; n < 8; ++n) {
            float2 mv = *(const float2*)&ms[n][f];  // ds_read_b64 broadcast
            float2 xv = *(const float2*)&xs[n][f];
            accA[n] += mv.x * wa0 + mv.y * wa1;
            accB[n] += xv.x * wb0 + xv.y * wb1;
            accC[n] += xv.x * wc0 + xv.y * wc1;
        }
    }
    float bj = b1[j];
    float blj = bl1[j];
    float out1[8];
#pragma unroll
    for (int n = 0; n < 8; ++n) {
        out1[n] = accA[n] * rdeg[n] + bj + accB[n];
        red[n][j] = out1[n] * out1[n];
    }
    __syncthreads();
    for (int stride = 128; stride > 0; stride >>= 1) {
        if (j < stride) {
#pragma unroll
            for (int n = 0; n < 8; ++n) red[n][j] += red[n][j + stride];
        }
        __syncthreads();
    }
#pragma unroll
    for (int n = 0; n < 8; ++n) {
        float rn = 1.0f / fmaxf(sqrtf(red[n][0]), 1e-12f);
        float z = out1[n] * rn + accC[n] + blj;
        h[(base + n) * HIDDEN + j] = z > 0.0f ? z : expm1f(z);
    }
}

// ---------------- p = h @ w2_l (bf16 out), float2 LDS dense loop ------------
__global__ __launch_bounds__(128) void project2_r14(
    const float* __restrict__ h, const float* __restrict__ w2l,
    bf16* __restrict__ pb) {
    __shared__ float hs[8][HIDDEN];
    int base = blockIdx.x * 8;
    int tid = threadIdx.x;
    for (int idx = tid; idx < 8 * HIDDEN; idx += 128) {
        int n = idx >> 8, k = idx & 255;
        hs[n][k] = h[(base + n) * HIDDEN + k];
    }
    __syncthreads();
    int j = tid;
    if (j >= NCLS) return;
    float acc[8] = {0};
    for (int k = 0; k < HIDDEN; k += 2) {
        float w0 = w2l[k * NCLS + j], w1 = w2l[(k + 1) * NCLS + j];
#pragma unroll
        for (int n = 0; n < 8; ++n) {
            float2 hv = *(const float2*)&hs[n][k];
            acc[n] += hv.x * w0 + hv.y * w1;
        }
    }
#pragma unroll
    for (int n = 0; n < 8; ++n)
        pb[(base + n) * PSTR + j] = __float2bfloat16(acc[n]);
}

// ---------------- layer 2 final: 8 nodes, 128 thr, float2 LDS dense loop ----
__global__ __launch_bounds__(128) void layer2_r14(
    const float* __restrict__ h, const bf16* __restrict__ pb,
    const int* __restrict__ off, const int* __restrict__ csr,
    const int* __restrict__ degi,
    const float* __restrict__ b2, const float* __restrict__ w2r,
    const float* __restrict__ wl2, const float* __restrict__ bl2,
    float* __restrict__ out) {
    __shared__ float hs[8][HIDDEN];
    __shared__ float mp[8][NCLS];
    __shared__ float red[8][128];
    __shared__ float rdeg[8];

    int base = blockIdx.x * 8;
    int tid = threadIdx.x;
    if (tid < 8) rdeg[tid] = 1.0f / fmaxf((float)degi[base + tid], 1.0f);
    for (int idx = tid; idx < 8 * HIDDEN; idx += 128) {
        int n = idx >> 8, k = idx & 255;
        hs[n][k] = h[(base + n) * HIDDEN + k];
    }
    // bf16 gather-aggregate of p, 4-way MLP
    for (int n = 0; n < 8; ++n) {
        int node = base + n;
        int e0 = off[node], e1 = off[node + 1];
        if (tid < NCLS) {
            float a0 = 0, a1 = 0, a2 = 0, a3 = 0;
            int e = e0;
            for (; e + 4 <= e1; e += 4) {
                int s0 = csr[e], s1 = csr[e + 1];
                int s2 = csr[e + 2], s3 = csr[e + 3];
                a0 += __bfloat162float(pb[s0 * PSTR + tid]);
                a1 += __bfloat162float(pb[s1 * PSTR + tid]);
                a2 += __bfloat162float(pb[s2 * PSTR + tid]);
                a3 += __bfloat162float(pb[s3 * PSTR + tid]);
            }
            for (; e < e1; ++e) a0 += __bfloat162float(pb[csr[e] * PSTR + tid]);
            mp[n][tid] = (a0 + a1) + (a2 + a3);
        }
    }
    __syncthreads();

    int j = tid;
    float accB[8] = {0}, accC[8] = {0};
    if (j < NCLS) {
        for (int k = 0; k < HIDDEN; k += 2) {
            float wb0 = w2r[k * NCLS + j], wb1 = w2r[(k + 1) * NCLS + j];
            float wc0 = wl2[k * NCLS + j], wc1 = wl2[(k + 1) * NCLS + j];
#pragma unroll
            for (int n = 0; n < 8; ++n) {
                float2 hv = *(const float2*)&hs[n][k];
                accB[n] += hv.x * wb0 + hv.y * wb1;
                accC[n] += hv.x * wc0 + hv.y * wc1;
            }
        }
    }
    float bj = (j < NCLS) ? b2[j] : 0.0f;
    float blj = (j < NCLS) ? bl2[j] : 0.0f;
    float out2[8];
#pragma unroll
    for (int n = 0; n < 8; ++n) {
        out2[n] = (j < NCLS) ? (mp[n][j] * rdeg[n] + bj + accB[n]) : 0.0f;
        red[n][j] = out2[n] * out2[n];
    }
    __syncthreads();
    for (int stride = 64; stride > 0; stride >>= 1) {
        if (j < stride) {
#pragma unroll
            for (int n = 0; n < 8; ++n) red[n][j] += red[n][j + stride];
        }
        __syncthreads();
    }
    if (j < NCLS) {
#pragma unroll
        for (int n = 0; n < 8; ++n) {
            float rn = 1.0f / fmaxf(sqrtf(red[n][0]), 1e-12f);
            out[(base + n) * NCLS + j] = out2[n] * rn + accC[n] + blj;
        }
    }
}

extern "C" void kernel_launch(void* const* d_in, const int* in_sizes, int n_in,
                              void* d_out, int out_size, void* d_ws, size_t ws_size,
                              hipStream_t stream) {
    const float* x   = (const float*)d_in[0];
    const int*   ei  = (const int*)d_in[1];
    const float* w1l = (const float*)d_in[2];
    const float* b1  = (const float*)d_in[3];
    const float* w1r = (const float*)d_in[4];
    const float* wl1 = (const float*)d_in[5];
    const float* bl1 = (const float*)d_in[6];
    const float* w2l = (const float*)d_in[7];
    const float* b2  = (const float*)d_in[8];
    const float* w2r = (const float*)d_in[9];
    const float* wl2 = (const float*)d_in[10];
    const float* bl2 = (const float*)d_in[11];
    float* out = (float*)d_out;

    const int* src = ei;
    const int* dst = ei + N_EDGES;

    int*   wsI  = (int*)d_ws;
    float* wsF  = (float*)d_ws;
    int*   degi = wsI;
    int*   off  = wsI + OFF_OFF;
    int*   cur  = wsI + OFF_CUR;
    int*   csr  = wsI + OFF_CSR;
    float* h    = wsF + OFF_H;
    bf16*  pb   = (bf16*)(wsF + OFF_PB);
    bf16*  xb   = (bf16*)(wsF + OFF_XB);

    hipMemsetAsync(degi, 0, (size_t)N_NODES * sizeof(int), stream);

    convx_r14<<<(N_NODES * IN_DIM + 255) / 256, 256, 0, stream>>>(x, xb);
    degcount_r14<<<(N_EDGES + 255) / 256, 256, 0, stream>>>(dst, degi);
    scan_r14<<<1, 256, 0, stream>>>(degi, off, cur);
    csrfill_r14<<<(N_EDGES + 255) / 256, 256, 0, stream>>>(src, dst, cur, csr);

    layer1_r14<<<N_NODES / 8, 256, 0, stream>>>(x, xb, off, csr, degi,
                                                w1l, b1, w1r, wl1, bl1, h);
    project2_r14<<<N_NODES / 8, 128, 0, stream>>>(h, w2l, pb);
    layer2_r14<<<N_NODES / 8, 128, 0, stream>>>(h, pb, off, csr, degi,
                                                b2, w2r, wl2, bl2, out);
}

// Round 15
// 518.880 us; speedup vs baseline: 2.4392x; 1.3279x over previous
//
#include <hip/hip_runtime.h>
#include <hip/hip_bf16.h>
#include <math.h>

typedef __hip_bfloat16 bf16;
typedef __attribute__((ext_vector_type(8))) short short8;
typedef __attribute__((ext_vector_type(4))) float f32x4;

#define N_NODES 50000
#define N_EDGES 800000
#define IN_DIM 50
#define HIDDEN 256
#define NCLS 121
#define PSTR 128     // padded stride for pb/qr/ql rows
#define NCOLT 24     // 384/16 column tiles in proj
#define LDSPITCH 264 // bf16 elements per LDS row (528 B -> 4-bank skew)

// ---- workspace layout (4-byte units) ----
// degi: int  [0,+50000)          off: [50048,+50001)     cur: [100112,+50000)
// csr : int  [150160,+800000)
// hb  : bf16 [950272, +6400000)   (50000*256 bf16)       ends  7350272
// pb  : bf16 [7350272, +3200000)  (50000*128 bf16)       ends 10550272
// xb  : bf16 [10550272, +1250000) (50000*50 bf16)        ends 11800272
// qr  : f32  [11800272, +6400000)                        ends 18200272
// ql  : f32  [18200272, +6400000)                        ends 24600272
// bw  : bf16 [24600272, +49152)   (8*384*32 bf16)        ends 24649424 (98.6 MB)
#define OFF_OFF  50048
#define OFF_CUR  100112
#define OFF_CSR  150160
#define OFF_HB   950272
#define OFF_PB   7350272
#define OFF_XB   10550272
#define OFF_QR   11800272
#define OFF_QL   18200272
#define OFF_BW   24600272

__device__ __forceinline__ int clampi(int v, int hi) {
    return v < 0 ? 0 : (v >= hi ? hi - 1 : v);
}

// ---------------- x -> bf16 copy ----------------
__global__ __launch_bounds__(256) void convx_r15(const float* __restrict__ x,
                                                 bf16* __restrict__ xb) {
    int i = blockIdx.x * 256 + threadIdx.x;
    if (i < N_NODES * IN_DIM) xb[i] = __float2bfloat16(x[i]);
}

// ---------------- pack [w2l|w2r|wl2] into MFMA B-fragment layout ------------
// bw[((kt*384 + c)*4 + q)*8 + j] = W[k=kt*32+q*8+j][c], zero-padded cls>=121
__global__ __launch_bounds__(256) void packw_r15(const float* __restrict__ w2l,
                                                 const float* __restrict__ w2r,
                                                 const float* __restrict__ wl2,
                                                 bf16* __restrict__ bw) {
    int i = blockIdx.x * 256 + threadIdx.x;
    if (i >= 8 * 384 * 32) return;
    int kt = i / 12288, r = i % 12288, c = r / 32, t32 = r % 32;
    int q = t32 >> 3, j = t32 & 7;
    int k = kt * 32 + q * 8 + j;
    int mat = c >> 7, cls = c & 127;
    float v = 0.0f;
    if (cls < NCLS) {
        const float* w = (mat == 0) ? w2l : ((mat == 1) ? w2r : wl2);
        v = w[k * NCLS + cls];
    }
    bw[i] = __float2bfloat16(v);
}

// ---------------- CSR build ----------------
__global__ __launch_bounds__(256) void degcount_r15(const int* __restrict__ dst,
                                                    int* __restrict__ degi) {
    int e = blockIdx.x * 256 + threadIdx.x;
    if (e < N_EDGES) atomicAdd(&degi[clampi(dst[e], N_NODES)], 1);
}

__global__ __launch_bounds__(256) void scan_r15(const int* __restrict__ degi,
                                                int* __restrict__ off,
                                                int* __restrict__ cur) {
    __shared__ int part[256];
    const int CH = (N_NODES + 255) / 256;
    int t = threadIdx.x;
    int begin = t * CH;
    int end = begin + CH < N_NODES ? begin + CH : N_NODES;
    int s = 0;
    for (int i = begin; i < end; ++i) s += degi[i];
    part[t] = s;
    __syncthreads();
    for (int d = 1; d < 256; d <<= 1) {
        int u = (t >= d) ? part[t - d] : 0;
        __syncthreads();
        part[t] += u;
        __syncthreads();
    }
    int run = part[t] - s;
    for (int i = begin; i < end; ++i) {
        off[i] = run;
        cur[i] = run;
        run += degi[i];
    }
    if (end == N_NODES) off[N_NODES] = run;
}

__global__ __launch_bounds__(256) void csrfill_r15(const int* __restrict__ src,
                                                   const int* __restrict__ dst,
                                                   int* __restrict__ cur,
                                                   int* __restrict__ csr) {
    int e = blockIdx.x * 256 + threadIdx.x;
    if (e >= N_EDGES) return;
    int d = clampi(dst[e], N_NODES);
    int pos = atomicAdd(&cur[d], 1);
    csr[pos] = clampi(src[e], N_NODES);
}

// ---------------- layer 1: 8 nodes, 256 thr (r10 structure, bf16 h out) -----
__global__ __launch_bounds__(256) void layer1_r15(
    const float* __restrict__ x, const bf16* __restrict__ xb,
    const int* __restrict__ off, const int* __restrict__ csr,
    const int* __restrict__ degi,
    const float* __restrict__ w1l, const float* __restrict__ b1,
    const float* __restrict__ w1r, const float* __restrict__ wl1,
    const float* __restrict__ bl1, bf16* __restrict__ hb) {
    __shared__ float xs[8][IN_DIM];
    __shared__ float ms[8][IN_DIM];
    __shared__ float red[8][HIDDEN];
    __shared__ float rdeg[8];

    int base = blockIdx.x * 8;
    int tid = threadIdx.x;
    int wave = tid >> 6, lane = tid & 63;

    if (tid < 8) rdeg[tid] = 1.0f / fmaxf((float)degi[base + tid], 1.0f);
    for (int idx = tid; idx < 8 * IN_DIM; idx += 256) {
        int n = idx / IN_DIM, f = idx % IN_DIM;
        xs[n][f] = x[(base + n) * IN_DIM + f];
    }
    for (int r = 0; r < 2; ++r) {
        int n = wave * 2 + r;
        int node = base + n;
        int e0 = off[node], e1 = off[node + 1];
        float a0 = 0, a1 = 0, a2 = 0, a3 = 0;
        int e = e0;
        for (; e + 4 <= e1; e += 4) {
            int s0 = csr[e], s1 = csr[e + 1], s2 = csr[e + 2], s3 = csr[e + 3];
            if (lane < IN_DIM) {
                a0 += __bfloat162float(xb[s0 * IN_DIM + lane]);
                a1 += __bfloat162float(xb[s1 * IN_DIM + lane]);
                a2 += __bfloat162float(xb[s2 * IN_DIM + lane]);
                a3 += __bfloat162float(xb[s3 * IN_DIM + lane]);
            }
        }
        for (; e < e1; ++e)
            if (lane < IN_DIM) a0 += __bfloat162float(xb[csr[e] * IN_DIM + lane]);
        if (lane < IN_DIM) ms[n][lane] = (a0 + a1) + (a2 + a3);
    }
    __syncthreads();

    int j = tid;  // hidden column; coalesced weight reads
    float accA[8] = {0}, accB[8] = {0}, accC[8] = {0};
    for (int f = 0; f < IN_DIM; ++f) {
        float wa = w1l[f * HIDDEN + j];
        float wb = w1r[f * HIDDEN + j];
        float wc = wl1[f * HIDDEN + j];
#pragma unroll
        for (int n = 0; n < 8; ++n) {
            accA[n] += ms[n][f] * wa;
            accB[n] += xs[n][f] * wb;
            accC[n] += xs[n][f] * wc;
        }
    }
    float bj = b1[j];
    float blj = bl1[j];
    float out1[8];
#pragma unroll
    for (int n = 0; n < 8; ++n) {
        out1[n] = accA[n] * rdeg[n] + bj + accB[n];
        red[n][j] = out1[n] * out1[n];
    }
    __syncthreads();
    for (int stride = 128; stride > 0; stride >>= 1) {
        if (j < stride) {
#pragma unroll
            for (int n = 0; n < 8; ++n) red[n][j] += red[n][j + stride];
        }
        __syncthreads();
    }
#pragma unroll
    for (int n = 0; n < 8; ++n) {
        float rn = 1.0f / fmaxf(sqrtf(red[n][0]), 1e-12f);
        float z = out1[n] * rn + accC[n] + blj;
        hb[(size_t)(base + n) * HIDDEN + j] =
            __float2bfloat16(z > 0.0f ? z : expm1f(z));
    }
}

// ---------------- MFMA projection: [16 nodes] x [384 cols] x K=256 ----------
__global__ __launch_bounds__(256) void proj_r15(
    const bf16* __restrict__ hb, const bf16* __restrict__ bw,
    bf16* __restrict__ pb, float* __restrict__ qr, float* __restrict__ ql) {
    __shared__ __align__(16) short hs_s[16 * LDSPITCH];

    int base = blockIdx.x * 16;
    int tid = threadIdx.x;
    // stage 16x256 bf16 h-tile
    {
        int row = tid >> 4, ch = tid & 15;
        const uint4* s =
            (const uint4*)((const short*)hb + (size_t)(base + row) * HIDDEN + ch * 16);
        uint4 v0 = s[0];
        *(uint4*)&hs_s[row * LDSPITCH + ch * 16] = v0;
    }
    {
        int row = tid >> 4, ch = tid & 15;
        const uint4* s =
            (const uint4*)((const short*)hb + (size_t)(base + row) * HIDDEN + ch * 16 + 8);
        uint4 v1 = s[0];
        *(uint4*)&hs_s[row * LDSPITCH + ch * 16 + 8] = v1;
    }
    __syncthreads();

    int wave = tid >> 6, lane = tid & 63;
    int rc = lane & 15, quad = lane >> 4;  // A-row / D-col index, quad

    short8 af[8];
#pragma unroll
    for (int kt = 0; kt < 8; ++kt)
        af[kt] = *(const short8*)&hs_s[rc * LDSPITCH + kt * 32 + quad * 8];

    const short* bws = (const short*)bw;
    for (int ti = 0; ti < NCOLT / 4; ++ti) {
        int t = wave * (NCOLT / 4) + ti;
        f32x4 acc = {0.0f, 0.0f, 0.0f, 0.0f};
#pragma unroll
        for (int kt = 0; kt < 8; ++kt) {
            short8 bf = *(const short8*)
                &bws[(((size_t)kt * 384 + t * 16 + rc) * 4 + quad) * 8];
            acc = __builtin_amdgcn_mfma_f32_16x16x32_bf16(af[kt], bf, acc, 0, 0, 0);
        }
        int col = t * 16 + rc;
        int mat = col >> 7, cls = col & 127;
#pragma unroll
        for (int r = 0; r < 4; ++r) {
            int node = base + quad * 4 + r;
            float v = acc[r];
            if (mat == 0)
                pb[(size_t)node * PSTR + cls] = __float2bfloat16(v);
            else if (mat == 1)
                qr[(size_t)node * PSTR + cls] = v;
            else
                ql[(size_t)node * PSTR + cls] = v;
        }
    }
}

// ---------------- final: gather pb + combine + normalize --------------------
__global__ __launch_bounds__(128) void final_r15(
    const bf16* __restrict__ pb, const float* __restrict__ qr,
    const float* __restrict__ ql, const int* __restrict__ off,
    const int* __restrict__ csr, const int* __restrict__ degi,
    const float* __restrict__ b2, const float* __restrict__ bl2,
    float* __restrict__ out) {
    __shared__ float mp[8][NCLS];
    __shared__ float red[8][128];
    __shared__ float rdeg[8];

    int base = blockIdx.x * 8;
    int tid = threadIdx.x;
    if (tid < 8) rdeg[tid] = 1.0f / fmaxf((float)degi[base + tid], 1.0f);
    // bf16 gather-aggregate of pb, 4-way MLP
    for (int n = 0; n < 8; ++n) {
        int node = base + n;
        int e0 = off[node], e1 = off[node + 1];
        if (tid < NCLS) {
            float a0 = 0, a1 = 0, a2 = 0, a3 = 0;
            int e = e0;
            for (; e + 4 <= e1; e += 4) {
                int s0 = csr[e], s1 = csr[e + 1];
                int s2 = csr[e + 2], s3 = csr[e + 3];
                a0 += __bfloat162float(pb[(size_t)s0 * PSTR + tid]);
                a1 += __bfloat162float(pb[(size_t)s1 * PSTR + tid]);
                a2 += __bfloat162float(pb[(size_t)s2 * PSTR + tid]);
                a3 += __bfloat162float(pb[(size_t)s3 * PSTR + tid]);
            }
            for (; e < e1; ++e)
                a0 += __bfloat162float(pb[(size_t)csr[e] * PSTR + tid]);
            mp[n][tid] = (a0 + a1) + (a2 + a3);
        }
    }
    __syncthreads();

    int j = tid;
    float bj = (j < NCLS) ? b2[j] : 0.0f;
    float blj = (j < NCLS) ? bl2[j] : 0.0f;
    float out2[8];
#pragma unroll
    for (int n = 0; n < 8; ++n) {
        out2[n] = (j < NCLS)
                      ? (mp[n][j] * rdeg[n] + bj + qr[(size_t)(base + n) * PSTR + j])
                      : 0.0f;
        red[n][j] = out2[n] * out2[n];
    }
    __syncthreads();
    for (int stride = 64; stride > 0; stride >>= 1) {
        if (j < stride) {
#pragma unroll
            for (int n = 0; n < 8; ++n) red[n][j] += red[n][j + stride];
        }
        __syncthreads();
    }
    if (j < NCLS) {
#pragma unroll
        for (int n = 0; n < 8; ++n) {
            float rn = 1.0f / fmaxf(sqrtf(red[n][0]), 1e-12f);
            out[(base + n) * NCLS + j] =
                out2[n] * rn + ql[(size_t)(base + n) * PSTR + j] + blj;
        }
    }
}

extern "C" void kernel_launch(void* const* d_in, const int* in_sizes, int n_in,
                              void* d_out, int out_size, void* d_ws, size_t ws_size,
                              hipStream_t stream) {
    const float* x   = (const float*)d_in[0];
    const int*   ei  = (const int*)d_in[1];
    const float* w1l = (const float*)d_in[2];
    const float* b1  = (const float*)d_in[3];
    const float* w1r = (const float*)d_in[4];
    const float* wl1 = (const float*)d_in[5];
    const float* bl1 = (const float*)d_in[6];
    const float* w2l = (const float*)d_in[7];
    const float* b2  = (const float*)d_in[8];
    const float* w2r = (const float*)d_in[9];
    const float* wl2 = (const float*)d_in[10];
    const float* bl2 = (const float*)d_in[11];
    float* out = (float*)d_out;

    const int* src = ei;
    const int* dst = ei + N_EDGES;

    int*   wsI  = (int*)d_ws;
    float* wsF  = (float*)d_ws;
    int*   degi = wsI;
    int*   off  = wsI + OFF_OFF;
    int*   cur  = wsI + OFF_CUR;
    int*   csr  = wsI + OFF_CSR;
    bf16*  hb   = (bf16*)(wsF + OFF_HB);
    bf16*  pb   = (bf16*)(wsF + OFF_PB);
    bf16*  xb   = (bf16*)(wsF + OFF_XB);
    float* qr   = wsF + OFF_QR;
    float* ql   = wsF + OFF_QL;
    bf16*  bw   = (bf16*)(wsF + OFF_BW);

    hipMemsetAsync(degi, 0, (size_t)N_NODES * sizeof(int), stream);

    convx_r15<<<(N_NODES * IN_DIM + 255) / 256, 256, 0, stream>>>(x, xb);
    packw_r15<<<(8 * 384 * 32 + 255) / 256, 256, 0, stream>>>(w2l, w2r, wl2, bw);
    degcount_r15<<<(N_EDGES + 255) / 256, 256, 0, stream>>>(dst, degi);
    scan_r15<<<1, 256, 0, stream>>>(degi, off, cur);
    csrfill_r15<<<(N_EDGES + 255) / 256, 256, 0, stream>>>(src, dst, cur, csr);

    layer1_r15<<<N_NODES / 8, 256, 0, stream>>>(x, xb, off, csr, degi,
                                                w1l, b1, w1r, wl1, bl1, hb);
    proj_r15<<<N_NODES / 16, 256, 0, stream>>>(hb, bw, pb, qr, ql);
    final_r15<<<N_NODES / 8, 128, 0, stream>>>(pb, qr, ql, off, csr, degi,
                                               b2, bl2, out);
}

// Round 16
// 475.748 us; speedup vs baseline: 2.6603x; 1.0907x over previous
//
#include <hip/hip_runtime.h>
#include <hip/hip_bf16.h>
#include <math.h>

typedef __hip_bfloat16 bf16;
typedef __attribute__((ext_vector_type(8))) short short8;
typedef __attribute__((ext_vector_type(4))) float f32x4;

#define N_NODES 50000
#define N_EDGES 800000
#define IN_DIM 50
#define HIDDEN 256
#define NCLS 121
#define PSTR 128     // padded stride for pb/qrb/qlb rows (bf16)
#define NCOLT 24     // 384/16 col tiles in proj2
#define LDSPITCH 264 // proj2 LDS pitch (bf16)

// ---- workspace layout (4-byte units) ----
// degi 0..50000 | off 50048.. | cur 100112.. | csr 150160..950160
// hb  bf16 50000x256 : [950272, 7350272)
// pb  bf16 50000x128 : [7350272, 10550272)
// ab  bf16 50000x128 : [10550272, 13750272)   A-operand: [mean|pad|x|pad]
// xb  bf16 50000x50  : [13750272, 15000272)
// qrb bf16 50000x128 : [15000272, 18200272)
// qlb bf16 50000x128 : [18200272, 21400272)
// bw  bf16 8*384*32  : [21400272, 21449424)
// bw1 bf16 4*512*32  : [21449424, 21482192)   total ~86 MB (ws >= 103 MB)
#define OFF_OFF  50048
#define OFF_CUR  100112
#define OFF_CSR  150160
#define OFF_HB   950272
#define OFF_PB   7350272
#define OFF_AB   10550272
#define OFF_XB   13750272
#define OFF_QRB  15000272
#define OFF_QLB  18200272
#define OFF_BW   21400272
#define OFF_BW1  21449424

__device__ __forceinline__ int clampi(int v, int hi) {
    return v < 0 ? 0 : (v >= hi ? hi - 1 : v);
}

// ---------------- convert x: fill ab row (zeros+x) and packed xb ------------
__global__ __launch_bounds__(256) void convx_r16(const float* __restrict__ x,
                                                 bf16* __restrict__ xb,
                                                 bf16* __restrict__ ab) {
    int i = blockIdx.x * 256 + threadIdx.x;
    if (i >= N_NODES * 128) return;
    int n = i >> 7, c = i & 127;
    float v = 0.0f;
    if (c >= 64 && c < 64 + IN_DIM) v = x[n * IN_DIM + (c - 64)];
    ab[i] = __float2bfloat16(v);
    if (c < IN_DIM) xb[n * IN_DIM + c] = __float2bfloat16(x[n * IN_DIM + c]);
}

// ---------------- pack layer-1 B: 128x512 = [w1l;w1r | 0;wl1] ---------------
__global__ __launch_bounds__(256) void packw1_r16(const float* __restrict__ w1l,
                                                  const float* __restrict__ w1r,
                                                  const float* __restrict__ wl1,
                                                  bf16* __restrict__ bw1) {
    int i = blockIdx.x * 256 + threadIdx.x;
    if (i >= 4 * 512 * 32) return;
    int kt = i / 16384, r = i % 16384, c = r / 32, t32 = r % 32;
    int q = t32 >> 3, j = t32 & 7;
    int k = kt * 32 + q * 8 + j;  // 0..127
    float v = 0.0f;
    if (k < 64) {
        if (k < IN_DIM && c < 256) v = w1l[k * HIDDEN + c];
    } else {
        int kr = k - 64;
        if (kr < IN_DIM)
            v = (c < 256) ? w1r[kr * HIDDEN + c] : wl1[kr * HIDDEN + (c - 256)];
    }
    bw1[i] = __float2bfloat16(v);
}

// ---------------- pack layer-2 B (verified r15 layout) ----------------------
__global__ __launch_bounds__(256) void packw2_r16(const float* __restrict__ w2l,
                                                  const float* __restrict__ w2r,
                                                  const float* __restrict__ wl2,
                                                  bf16* __restrict__ bw) {
    int i = blockIdx.x * 256 + threadIdx.x;
    if (i >= 8 * 384 * 32) return;
    int kt = i / 12288, r = i % 12288, c = r / 32, t32 = r % 32;
    int q = t32 >> 3, j = t32 & 7;
    int k = kt * 32 + q * 8 + j;
    int mat = c >> 7, cls = c & 127;
    float v = 0.0f;
    if (cls < NCLS) {
        const float* w = (mat == 0) ? w2l : ((mat == 1) ? w2r : wl2);
        v = w[k * NCLS + cls];
    }
    bw[i] = __float2bfloat16(v);
}

// ---------------- CSR build ----------------
__global__ __launch_bounds__(256) void degcount_r16(const int* __restrict__ dst,
                                                    int* __restrict__ degi) {
    int e = blockIdx.x * 256 + threadIdx.x;
    if (e < N_EDGES) atomicAdd(&degi[clampi(dst[e], N_NODES)], 1);
}

__global__ __launch_bounds__(256) void scan_r16(const int* __restrict__ degi,
                                                int* __restrict__ off,
                                                int* __restrict__ cur) {
    __shared__ int part[256];
    const int CH = (N_NODES + 255) / 256;
    int t = threadIdx.x;
    int begin = t * CH;
    int end = begin + CH < N_NODES ? begin + CH : N_NODES;
    int s = 0;
    for (int i = begin; i < end; ++i) s += degi[i];
    part[t] = s;
    __syncthreads();
    for (int d = 1; d < 256; d <<= 1) {
        int u = (t >= d) ? part[t - d] : 0;
        __syncthreads();
        part[t] += u;
        __syncthreads();
    }
    int run = part[t] - s;
    for (int i = begin; i < end; ++i) {
        off[i] = run;
        cur[i] = run;
        run += degi[i];
    }
    if (end == N_NODES) off[N_NODES] = run;
}

__global__ __launch_bounds__(256) void csrfill_r16(const int* __restrict__ src,
                                                   const int* __restrict__ dst,
                                                   int* __restrict__ cur,
                                                   int* __restrict__ csr) {
    int e = blockIdx.x * 256 + threadIdx.x;
    if (e >= N_EDGES) return;
    int d = clampi(dst[e], N_NODES);
    int pos = atomicAdd(&cur[d], 1);
    csr[pos] = clampi(src[e], N_NODES);
}

// ---------------- gather1: mean-aggregate x (uint-vectorized) ---------------
__global__ __launch_bounds__(256) void gather1_r16(
    const unsigned int* __restrict__ xbu, const int* __restrict__ off,
    const int* __restrict__ csr, const int* __restrict__ degi,
    unsigned int* __restrict__ abu) {
    __shared__ float rdeg[8];
    int base = blockIdx.x * 8;
    int tid = threadIdx.x;
    if (tid < 8) rdeg[tid] = 1.0f / fmaxf((float)degi[base + tid], 1.0f);
    __syncthreads();
    int wave = tid >> 6, lane = tid & 63;
    for (int r = 0; r < 2; ++r) {
        int n = wave * 2 + r;
        int node = base + n;
        int e0 = off[node], e1 = off[node + 1];
        if (lane < 25) {
            float ax0 = 0, ay0 = 0, ax1 = 0, ay1 = 0;
            float ax2 = 0, ay2 = 0, ax3 = 0, ay3 = 0;
            int e = e0;
            for (; e + 4 <= e1; e += 4) {
                unsigned u0 = xbu[(size_t)csr[e] * 25 + lane];
                unsigned u1 = xbu[(size_t)csr[e + 1] * 25 + lane];
                unsigned u2 = xbu[(size_t)csr[e + 2] * 25 + lane];
                unsigned u3 = xbu[(size_t)csr[e + 3] * 25 + lane];
                ax0 += __uint_as_float(u0 << 16);
                ay0 += __uint_as_float(u0 & 0xffff0000u);
                ax1 += __uint_as_float(u1 << 16);
                ay1 += __uint_as_float(u1 & 0xffff0000u);
                ax2 += __uint_as_float(u2 << 16);
                ay2 += __uint_as_float(u2 & 0xffff0000u);
                ax3 += __uint_as_float(u3 << 16);
                ay3 += __uint_as_float(u3 & 0xffff0000u);
            }
            for (; e < e1; ++e) {
                unsigned u0 = xbu[(size_t)csr[e] * 25 + lane];
                ax0 += __uint_as_float(u0 << 16);
                ay0 += __uint_as_float(u0 & 0xffff0000u);
            }
            float mx = ((ax0 + ax1) + (ax2 + ax3)) * rdeg[n];
            float my = ((ay0 + ay1) + (ay2 + ay3)) * rdeg[n];
            bf16 bx = __float2bfloat16(mx), by = __float2bfloat16(my);
            unsigned pack = (unsigned)*(unsigned short*)&bx |
                            ((unsigned)*(unsigned short*)&by << 16);
            abu[(size_t)node * 64 + lane] = pack;
        }
    }
}

// ---------------- proj1 (MFMA): [mean|x] @ B1 + norm/ELU epilogue -----------
__global__ __launch_bounds__(256) void proj1_r16(
    const bf16* __restrict__ ab_, const bf16* __restrict__ bw1,
    const float* __restrict__ b1, const float* __restrict__ bl1,
    bf16* __restrict__ hb) {
    __shared__ float os[16][516];  // pitch 516: 4-row stride != 0 mod 32
    __shared__ float partial[16][17];
    __shared__ float rns[16];

    int base = blockIdx.x * 16;
    int tid = threadIdx.x;
    int wave = tid >> 6, lane = tid & 63;
    int rc = lane & 15, quad = lane >> 4;

    const short* ab = (const short*)ab_;
    short8 af[4];
#pragma unroll
    for (int kt = 0; kt < 4; ++kt)
        af[kt] = *(const short8*)&ab[(size_t)(base + rc) * 128 + kt * 32 + quad * 8];

    const short* bws = (const short*)bw1;
    for (int ti = 0; ti < 8; ++ti) {
        int t = wave * 8 + ti;
        f32x4 acc = {0.0f, 0.0f, 0.0f, 0.0f};
#pragma unroll
        for (int kt = 0; kt < 4; ++kt) {
            short8 bf = *(const short8*)
                &bws[(((size_t)kt * 512 + t * 16 + rc) * 4 + quad) * 8];
            acc = __builtin_amdgcn_mfma_f32_16x16x32_bf16(af[kt], bf, acc, 0, 0, 0);
        }
        int col = t * 16 + rc;
#pragma unroll
        for (int r = 0; r < 4; ++r) os[quad * 4 + r][col] = acc[r];
    }
    __syncthreads();
    // sum of squares of out1 = os[:,0:256] + b1
    {
        int n = tid & 15, jj = tid >> 4;
        float s = 0.0f;
#pragma unroll
        for (int c = 0; c < 16; ++c) {
            int cc = jj * 16 + c;
            float v = os[n][cc] + b1[cc];
            s += v * v;
        }
        partial[n][jj] = s;
    }
    __syncthreads();
    if (tid < 16) {
        float s = 0.0f;
#pragma unroll
        for (int jj = 0; jj < 16; ++jj) s += partial[tid][jj];
        rns[tid] = 1.0f / fmaxf(sqrtf(s), 1e-12f);
    }
    __syncthreads();
    for (int i = 0; i < 16; ++i) {
        int idx = i * 256 + tid;
        int n = idx >> 8, c = idx & 255;
        float z = (os[n][c] + b1[c]) * rns[n] + os[n][256 + c] + bl1[c];
        hb[(size_t)(base + n) * HIDDEN + c] =
            __float2bfloat16(z > 0.0f ? z : expm1f(z));
    }
}

// ---------------- proj2 (MFMA, r15-verified): h @ [w2l|w2r|wl2] -------------
__global__ __launch_bounds__(256) void proj2_r16(
    const bf16* __restrict__ hb, const bf16* __restrict__ bw,
    bf16* __restrict__ pb, bf16* __restrict__ qrb, bf16* __restrict__ qlb) {
    __shared__ __align__(16) short hs_s[16 * LDSPITCH];

    int base = blockIdx.x * 16;
    int tid = threadIdx.x;
    {
        int row = tid >> 4, ch = tid & 15;
        const uint4* s =
            (const uint4*)((const short*)hb + (size_t)(base + row) * HIDDEN + ch * 16);
        uint4 v0 = s[0];
        *(uint4*)&hs_s[row * LDSPITCH + ch * 16] = v0;
    }
    {
        int row = tid >> 4, ch = tid & 15;
        const uint4* s =
            (const uint4*)((const short*)hb + (size_t)(base + row) * HIDDEN + ch * 16 + 8);
        uint4 v1 = s[0];
        *(uint4*)&hs_s[row * LDSPITCH + ch * 16 + 8] = v1;
    }
    __syncthreads();

    int wave = tid >> 6, lane = tid & 63;
    int rc = lane & 15, quad = lane >> 4;

    short8 af[8];
#pragma unroll
    for (int kt = 0; kt < 8; ++kt)
        af[kt] = *(const short8*)&hs_s[rc * LDSPITCH + kt * 32 + quad * 8];

    const short* bws = (const short*)bw;
    for (int ti = 0; ti < NCOLT / 4; ++ti) {
        int t = wave * (NCOLT / 4) + ti;
        f32x4 acc = {0.0f, 0.0f, 0.0f, 0.0f};
#pragma unroll
        for (int kt = 0; kt < 8; ++kt) {
            short8 bf = *(const short8*)
                &bws[(((size_t)kt * 384 + t * 16 + rc) * 4 + quad) * 8];
            acc = __builtin_amdgcn_mfma_f32_16x16x32_bf16(af[kt], bf, acc, 0, 0, 0);
        }
        int col = t * 16 + rc;
        int mat = col >> 7, cls = col & 127;
#pragma unroll
        for (int r = 0; r < 4; ++r) {
            int node = base + quad * 4 + r;
            bf16 v = __float2bfloat16(acc[r]);
            if (mat == 0)
                pb[(size_t)node * PSTR + cls] = v;
            else if (mat == 1)
                qrb[(size_t)node * PSTR + cls] = v;
            else
                qlb[(size_t)node * PSTR + cls] = v;
        }
    }
}

// ---------------- final: gather pb (uint-vectorized) + combine + norm -------
__global__ __launch_bounds__(128) void final_r16(
    const unsigned int* __restrict__ pbu, const bf16* __restrict__ qrb,
    const bf16* __restrict__ qlb, const int* __restrict__ off,
    const int* __restrict__ csr, const int* __restrict__ degi,
    const float* __restrict__ b2, const float* __restrict__ bl2,
    float* __restrict__ out) {
    __shared__ float mp[8][128];
    __shared__ float red[8][128];
    __shared__ float rdeg[8];

    int base = blockIdx.x * 8;
    int tid = threadIdx.x;
    if (tid < 8) rdeg[tid] = 1.0f / fmaxf((float)degi[base + tid], 1.0f);
    for (int n = 0; n < 8; ++n) {
        int node = base + n;
        int e0 = off[node], e1 = off[node + 1];
        if (tid < 64) {
            float ax0 = 0, ay0 = 0, ax1 = 0, ay1 = 0;
            float ax2 = 0, ay2 = 0, ax3 = 0, ay3 = 0;
            int e = e0;
            for (; e + 4 <= e1; e += 4) {
                unsigned u0 = pbu[(size_t)csr[e] * 64 + tid];
                unsigned u1 = pbu[(size_t)csr[e + 1] * 64 + tid];
                unsigned u2 = pbu[(size_t)csr[e + 2] * 64 + tid];
                unsigned u3 = pbu[(size_t)csr[e + 3] * 64 + tid];
                ax0 += __uint_as_float(u0 << 16);
                ay0 += __uint_as_float(u0 & 0xffff0000u);
                ax1 += __uint_as_float(u1 << 16);
                ay1 += __uint_as_float(u1 & 0xffff0000u);
                ax2 += __uint_as_float(u2 << 16);
                ay2 += __uint_as_float(u2 & 0xffff0000u);
                ax3 += __uint_as_float(u3 << 16);
                ay3 += __uint_as_float(u3 & 0xffff0000u);
            }
            for (; e < e1; ++e) {
                unsigned u0 = pbu[(size_t)csr[e] * 64 + tid];
                ax0 += __uint_as_float(u0 << 16);
                ay0 += __uint_as_float(u0 & 0xffff0000u);
            }
            mp[n][2 * tid] = (ax0 + ax1) + (ax2 + ax3);
            mp[n][2 * tid + 1] = (ay0 + ay1) + (ay2 + ay3);
        }
    }
    __syncthreads();

    int j = tid;
    float bj = (j < NCLS) ? b2[j] : 0.0f;
    float blj = (j < NCLS) ? bl2[j] : 0.0f;
    float out2[8];
#pragma unroll
    for (int n = 0; n < 8; ++n) {
        out2[n] = (j < NCLS)
                      ? (mp[n][j] * rdeg[n] + bj +
                         __bfloat162float(qrb[(size_t)(base + n) * PSTR + j]))
                      : 0.0f;
        red[n][j] = out2[n] * out2[n];
    }
    __syncthreads();
    for (int stride = 64; stride > 0; stride >>= 1) {
        if (j < stride) {
#pragma unroll
            for (int n = 0; n < 8; ++n) red[n][j] += red[n][j + stride];
        }
        __syncthreads();
    }
    if (j < NCLS) {
#pragma unroll
        for (int n = 0; n < 8; ++n) {
            float rn = 1.0f / fmaxf(sqrtf(red[n][0]), 1e-12f);
            out[(base + n) * NCLS + j] =
                out2[n] * rn +
                __bfloat162float(qlb[(size_t)(base + n) * PSTR + j]) + blj;
        }
    }
}

extern "C" void kernel_launch(void* const* d_in, const int* in_sizes, int n_in,
                              void* d_out, int out_size, void* d_ws, size_t ws_size,
                              hipStream_t stream) {
    const float* x   = (const float*)d_in[0];
    const int*   ei  = (const int*)d_in[1];
    const float* w1l = (const float*)d_in[2];
    const float* b1  = (const float*)d_in[3];
    const float* w1r = (const float*)d_in[4];
    const float* wl1 = (const float*)d_in[5];
    const float* bl1 = (const float*)d_in[6];
    const float* w2l = (const float*)d_in[7];
    const float* b2  = (const float*)d_in[8];
    const float* w2r = (const float*)d_in[9];
    const float* wl2 = (const float*)d_in[10];
    const float* bl2 = (const float*)d_in[11];
    float* out = (float*)d_out;

    const int* src = ei;
    const int* dst = ei + N_EDGES;

    int*   wsI  = (int*)d_ws;
    float* wsF  = (float*)d_ws;
    int*   degi = wsI;
    int*   off  = wsI + OFF_OFF;
    int*   cur  = wsI + OFF_CUR;
    int*   csr  = wsI + OFF_CSR;
    bf16*  hb   = (bf16*)(wsF + OFF_HB);
    bf16*  pb   = (bf16*)(wsF + OFF_PB);
    bf16*  ab   = (bf16*)(wsF + OFF_AB);
    bf16*  xb   = (bf16*)(wsF + OFF_XB);
    bf16*  qrb  = (bf16*)(wsF + OFF_QRB);
    bf16*  qlb  = (bf16*)(wsF + OFF_QLB);
    bf16*  bw   = (bf16*)(wsF + OFF_BW);
    bf16*  bw1  = (bf16*)(wsF + OFF_BW1);

    hipMemsetAsync(degi, 0, (size_t)N_NODES * sizeof(int), stream);

    convx_r16<<<(N_NODES * 128 + 255) / 256, 256, 0, stream>>>(x, xb, ab);
    packw1_r16<<<(4 * 512 * 32 + 255) / 256, 256, 0, stream>>>(w1l, w1r, wl1, bw1);
    packw2_r16<<<(8 * 384 * 32 + 255) / 256, 256, 0, stream>>>(w2l, w2r, wl2, bw);
    degcount_r16<<<(N_EDGES + 255) / 256, 256, 0, stream>>>(dst, degi);
    scan_r16<<<1, 256, 0, stream>>>(degi, off, cur);
    csrfill_r16<<<(N_EDGES + 255) / 256, 256, 0, stream>>>(src, dst, cur, csr);

    gather1_r16<<<N_NODES / 8, 256, 0, stream>>>((const unsigned int*)xb, off,
                                                 csr, degi, (unsigned int*)ab);
    proj1_r16<<<N_NODES / 16, 256, 0, stream>>>(ab, bw1, b1, bl1, hb);
    proj2_r16<<<N_NODES / 16, 256, 0, stream>>>(hb, bw, pb, qrb, qlb);
    final_r16<<<N_NODES / 8, 128, 0, stream>>>((const unsigned int*)pb, qrb, qlb,
                                               off, csr, degi, b2, bl2, out);
}

// Round 17
// 357.800 us; speedup vs baseline: 3.5373x; 1.3296x over previous
//
#include <hip/hip_runtime.h>
#include <hip/hip_bf16.h>
#include <math.h>

typedef __hip_bfloat16 bf16;
typedef __attribute__((ext_vector_type(8))) short short8;
typedef __attribute__((ext_vector_type(4))) float f32x4;

#define N_NODES 50000
#define N_EDGES 800000
#define IN_DIM 50
#define HIDDEN 256
#define NCLS 121
#define PSTR 128     // padded stride for pb/qrb/qlb rows (bf16)
#define NCOLT 24     // 384/16 col tiles in proj2
#define LDSPITCH 264 // proj2 LDS pitch (bf16)
#define NCHUNK 196   // ceil(50000/256) scan chunks

// ---- workspace layout (4-byte units) ----
// degi 0..50000 | off 50048.. | cur 100112.. | csr 150160..950160
// hb  bf16 50000x256 : [950272, 7350272)
// pb  bf16 50000x128 : [7350272, 10550272)
// ab  bf16 50000x128 : [10550272, 13750272)
// xb  bf16 50000x50  : [13750272, 15000272)
// qrb bf16 50000x128 : [15000272, 18200272)
// qlb bf16 50000x128 : [18200272, 21400272)
// bw  bf16 8*384*32  : [21400272, 21449424)
// bw1 bf16 4*512*32  : [21449424, 21482192)
// csum int [21482240,+196) | cbase int [21482496,+196)   (~86 MB total)
#define OFF_OFF   50048
#define OFF_CUR   100112
#define OFF_CSR   150160
#define OFF_HB    950272
#define OFF_PB    7350272
#define OFF_AB    10550272
#define OFF_XB    13750272
#define OFF_QRB   15000272
#define OFF_QLB   18200272
#define OFF_BW    21400272
#define OFF_BW1   21449424
#define OFF_CSUM  21482240
#define OFF_CBASE 21482496

__device__ __forceinline__ int clampi(int v, int hi) {
    return v < 0 ? 0 : (v >= hi ? hi - 1 : v);
}

// ---------------- convert x: fill ab row (zeros+x) and packed xb ------------
__global__ __launch_bounds__(256) void convx_r17(const float* __restrict__ x,
                                                 bf16* __restrict__ xb,
                                                 bf16* __restrict__ ab) {
    int i = blockIdx.x * 256 + threadIdx.x;
    if (i >= N_NODES * 128) return;
    int n = i >> 7, c = i & 127;
    float v = 0.0f;
    if (c >= 64 && c < 64 + IN_DIM) v = x[n * IN_DIM + (c - 64)];
    ab[i] = __float2bfloat16(v);
    if (c < IN_DIM) xb[n * IN_DIM + c] = __float2bfloat16(x[n * IN_DIM + c]);
}

// ---------------- pack layer-1 B: 128x512 = [w1l;w1r | 0;wl1] ---------------
__global__ __launch_bounds__(256) void packw1_r17(const float* __restrict__ w1l,
                                                  const float* __restrict__ w1r,
                                                  const float* __restrict__ wl1,
                                                  bf16* __restrict__ bw1) {
    int i = blockIdx.x * 256 + threadIdx.x;
    if (i >= 4 * 512 * 32) return;
    int kt = i / 16384, r = i % 16384, c = r / 32, t32 = r % 32;
    int q = t32 >> 3, j = t32 & 7;
    int k = kt * 32 + q * 8 + j;  // 0..127
    float v = 0.0f;
    if (k < 64) {
        if (k < IN_DIM && c < 256) v = w1l[k * HIDDEN + c];
    } else {
        int kr = k - 64;
        if (kr < IN_DIM)
            v = (c < 256) ? w1r[kr * HIDDEN + c] : wl1[kr * HIDDEN + (c - 256)];
    }
    bw1[i] = __float2bfloat16(v);
}

// ---------------- pack layer-2 B (verified r15 layout) ----------------------
__global__ __launch_bounds__(256) void packw2_r17(const float* __restrict__ w2l,
                                                  const float* __restrict__ w2r,
                                                  const float* __restrict__ wl2,
                                                  bf16* __restrict__ bw) {
    int i = blockIdx.x * 256 + threadIdx.x;
    if (i >= 8 * 384 * 32) return;
    int kt = i / 12288, r = i % 12288, c = r / 32, t32 = r % 32;
    int q = t32 >> 3, j = t32 & 7;
    int k = kt * 32 + q * 8 + j;
    int mat = c >> 7, cls = c & 127;
    float v = 0.0f;
    if (cls < NCLS) {
        const float* w = (mat == 0) ? w2l : ((mat == 1) ? w2r : wl2);
        v = w[k * NCLS + cls];
    }
    bw[i] = __float2bfloat16(v);
}

// ---------------- CSR build: degcount ----------------
__global__ __launch_bounds__(256) void degcount_r17(const int* __restrict__ dst,
                                                    int* __restrict__ degi) {
    int e = blockIdx.x * 256 + threadIdx.x;
    if (e < N_EDGES) atomicAdd(&degi[clampi(dst[e], N_NODES)], 1);
}

// ---------------- 3-phase parallel exclusive scan ----------------
__global__ __launch_bounds__(256) void chunksum_r17(const int* __restrict__ degi,
                                                    int* __restrict__ csum) {
    __shared__ int red[256];
    int i = blockIdx.x * 256 + threadIdx.x;
    red[threadIdx.x] = (i < N_NODES) ? degi[i] : 0;
    __syncthreads();
    for (int s = 128; s > 0; s >>= 1) {
        if (threadIdx.x < s) red[threadIdx.x] += red[threadIdx.x + s];
        __syncthreads();
    }
    if (threadIdx.x == 0) csum[blockIdx.x] = red[0];
}

__global__ __launch_bounds__(256) void scanchunks_r17(const int* __restrict__ csum,
                                                      int* __restrict__ cbase,
                                                      int* __restrict__ off) {
    __shared__ int s[256];
    int t = threadIdx.x;
    int v = (t < NCHUNK) ? csum[t] : 0;
    s[t] = v;
    __syncthreads();
    for (int d = 1; d < 256; d <<= 1) {
        int u = (t >= d) ? s[t - d] : 0;
        __syncthreads();
        s[t] += u;
        __syncthreads();
    }
    if (t < NCHUNK) cbase[t] = s[t] - v;  // exclusive chunk base
    if (t == 255) off[N_NODES] = s[255];  // grand total
}

__global__ __launch_bounds__(256) void scatteroff_r17(const int* __restrict__ degi,
                                                      const int* __restrict__ cbase,
                                                      int* __restrict__ off,
                                                      int* __restrict__ cur) {
    __shared__ int s[256];
    int i = blockIdx.x * 256 + threadIdx.x;
    int t = threadIdx.x;
    int v = (i < N_NODES) ? degi[i] : 0;
    s[t] = v;
    __syncthreads();
    for (int d = 1; d < 256; d <<= 1) {
        int u = (t >= d) ? s[t - d] : 0;
        __syncthreads();
        s[t] += u;
        __syncthreads();
    }
    int ex = s[t] - v + cbase[blockIdx.x];
    if (i < N_NODES) {
        off[i] = ex;
        cur[i] = ex;
    }
}

__global__ __launch_bounds__(256) void csrfill_r17(const int* __restrict__ src,
                                                   const int* __restrict__ dst,
                                                   int* __restrict__ cur,
                                                   int* __restrict__ csr) {
    int e = blockIdx.x * 256 + threadIdx.x;
    if (e >= N_EDGES) return;
    int d = clampi(dst[e], N_NODES);
    int pos = atomicAdd(&cur[d], 1);
    csr[pos] = clampi(src[e], N_NODES);
}

// ---------------- gather1: mean-aggregate x (uint-vectorized) ---------------
__global__ __launch_bounds__(256) void gather1_r17(
    const unsigned int* __restrict__ xbu, const int* __restrict__ off,
    const int* __restrict__ csr, const int* __restrict__ degi,
    unsigned int* __restrict__ abu) {
    __shared__ float rdeg[8];
    int base = blockIdx.x * 8;
    int tid = threadIdx.x;
    if (tid < 8) rdeg[tid] = 1.0f / fmaxf((float)degi[base + tid], 1.0f);
    __syncthreads();
    int wave = tid >> 6, lane = tid & 63;
    for (int r = 0; r < 2; ++r) {
        int n = wave * 2 + r;
        int node = base + n;
        int e0 = off[node], e1 = off[node + 1];
        if (lane < 25) {
            float ax0 = 0, ay0 = 0, ax1 = 0, ay1 = 0;
            float ax2 = 0, ay2 = 0, ax3 = 0, ay3 = 0;
            int e = e0;
            for (; e + 4 <= e1; e += 4) {
                unsigned u0 = xbu[(size_t)csr[e] * 25 + lane];
                unsigned u1 = xbu[(size_t)csr[e + 1] * 25 + lane];
                unsigned u2 = xbu[(size_t)csr[e + 2] * 25 + lane];
                unsigned u3 = xbu[(size_t)csr[e + 3] * 25 + lane];
                ax0 += __uint_as_float(u0 << 16);
                ay0 += __uint_as_float(u0 & 0xffff0000u);
                ax1 += __uint_as_float(u1 << 16);
                ay1 += __uint_as_float(u1 & 0xffff0000u);
                ax2 += __uint_as_float(u2 << 16);
                ay2 += __uint_as_float(u2 & 0xffff0000u);
                ax3 += __uint_as_float(u3 << 16);
                ay3 += __uint_as_float(u3 & 0xffff0000u);
            }
            for (; e < e1; ++e) {
                unsigned u0 = xbu[(size_t)csr[e] * 25 + lane];
                ax0 += __uint_as_float(u0 << 16);
                ay0 += __uint_as_float(u0 & 0xffff0000u);
            }
            float mx = ((ax0 + ax1) + (ax2 + ax3)) * rdeg[n];
            float my = ((ay0 + ay1) + (ay2 + ay3)) * rdeg[n];
            bf16 bx = __float2bfloat16(mx), by = __float2bfloat16(my);
            unsigned pack = (unsigned)*(unsigned short*)&bx |
                            ((unsigned)*(unsigned short*)&by << 16);
            abu[(size_t)node * 64 + lane] = pack;
        }
    }
}

// ---------------- proj1 (MFMA): [mean|x] @ B1 + norm/ELU epilogue -----------
__global__ __launch_bounds__(256) void proj1_r17(
    const bf16* __restrict__ ab_, const bf16* __restrict__ bw1,
    const float* __restrict__ b1, const float* __restrict__ bl1,
    bf16* __restrict__ hb) {
    __shared__ float os[16][516];
    __shared__ float partial[16][17];
    __shared__ float rns[16];

    int base = blockIdx.x * 16;
    int tid = threadIdx.x;
    int wave = tid >> 6, lane = tid & 63;
    int rc = lane & 15, quad = lane >> 4;

    const short* ab = (const short*)ab_;
    short8 af[4];
#pragma unroll
    for (int kt = 0; kt < 4; ++kt)
        af[kt] = *(const short8*)&ab[(size_t)(base + rc) * 128 + kt * 32 + quad * 8];

    const short* bws = (const short*)bw1;
    for (int ti = 0; ti < 8; ++ti) {
        int t = wave * 8 + ti;
        f32x4 acc = {0.0f, 0.0f, 0.0f, 0.0f};
#pragma unroll
        for (int kt = 0; kt < 4; ++kt) {
            short8 bf = *(const short8*)
                &bws[(((size_t)kt * 512 + t * 16 + rc) * 4 + quad) * 8];
            acc = __builtin_amdgcn_mfma_f32_16x16x32_bf16(af[kt], bf, acc, 0, 0, 0);
        }
        int col = t * 16 + rc;
#pragma unroll
        for (int r = 0; r < 4; ++r) os[quad * 4 + r][col] = acc[r];
    }
    __syncthreads();
    {
        int n = tid & 15, jj = tid >> 4;
        float s = 0.0f;
#pragma unroll
        for (int c = 0; c < 16; ++c) {
            int cc = jj * 16 + c;
            float v = os[n][cc] + b1[cc];
            s += v * v;
        }
        partial[n][jj] = s;
    }
    __syncthreads();
    if (tid < 16) {
        float s = 0.0f;
#pragma unroll
        for (int jj = 0; jj < 16; ++jj) s += partial[tid][jj];
        rns[tid] = 1.0f / fmaxf(sqrtf(s), 1e-12f);
    }
    __syncthreads();
    for (int i = 0; i < 16; ++i) {
        int idx = i * 256 + tid;
        int n = idx >> 8, c = idx & 255;
        float z = (os[n][c] + b1[c]) * rns[n] + os[n][256 + c] + bl1[c];
        hb[(size_t)(base + n) * HIDDEN + c] =
            __float2bfloat16(z > 0.0f ? z : expm1f(z));
    }
}

// ---------------- proj2 (MFMA, verified): h @ [w2l|w2r|wl2] -----------------
__global__ __launch_bounds__(256) void proj2_r17(
    const bf16* __restrict__ hb, const bf16* __restrict__ bw,
    bf16* __restrict__ pb, bf16* __restrict__ qrb, bf16* __restrict__ qlb) {
    __shared__ __align__(16) short hs_s[16 * LDSPITCH];

    int base = blockIdx.x * 16;
    int tid = threadIdx.x;
    {
        int row = tid >> 4, ch = tid & 15;
        const uint4* s =
            (const uint4*)((const short*)hb + (size_t)(base + row) * HIDDEN + ch * 16);
        uint4 v0 = s[0];
        *(uint4*)&hs_s[row * LDSPITCH + ch * 16] = v0;
    }
    {
        int row = tid >> 4, ch = tid & 15;
        const uint4* s =
            (const uint4*)((const short*)hb + (size_t)(base + row) * HIDDEN + ch * 16 + 8);
        uint4 v1 = s[0];
        *(uint4*)&hs_s[row * LDSPITCH + ch * 16 + 8] = v1;
    }
    __syncthreads();

    int wave = tid >> 6, lane = tid & 63;
    int rc = lane & 15, quad = lane >> 4;

    short8 af[8];
#pragma unroll
    for (int kt = 0; kt < 8; ++kt)
        af[kt] = *(const short8*)&hs_s[rc * LDSPITCH + kt * 32 + quad * 8];

    const short* bws = (const short*)bw;
    for (int ti = 0; ti < NCOLT / 4; ++ti) {
        int t = wave * (NCOLT / 4) + ti;
        f32x4 acc = {0.0f, 0.0f, 0.0f, 0.0f};
#pragma unroll
        for (int kt = 0; kt < 8; ++kt) {
            short8 bf = *(const short8*)
                &bws[(((size_t)kt * 384 + t * 16 + rc) * 4 + quad) * 8];
            acc = __builtin_amdgcn_mfma_f32_16x16x32_bf16(af[kt], bf, acc, 0, 0, 0);
        }
        int col = t * 16 + rc;
        int mat = col >> 7, cls = col & 127;
#pragma unroll
        for (int r = 0; r < 4; ++r) {
            int node = base + quad * 4 + r;
            bf16 v = __float2bfloat16(acc[r]);
            if (mat == 0)
                pb[(size_t)node * PSTR + cls] = v;
            else if (mat == 1)
                qrb[(size_t)node * PSTR + cls] = v;
            else
                qlb[(size_t)node * PSTR + cls] = v;
        }
    }
}

// ---------------- final: gather pb (uint-vectorized) + combine + norm -------
__global__ __launch_bounds__(128) void final_r17(
    const unsigned int* __restrict__ pbu, const bf16* __restrict__ qrb,
    const bf16* __restrict__ qlb, const int* __restrict__ off,
    const int* __restrict__ csr, const int* __restrict__ degi,
    const float* __restrict__ b2, const float* __restrict__ bl2,
    float* __restrict__ out) {
    __shared__ float mp[8][128];
    __shared__ float red[8][128];
    __shared__ float rdeg[8];

    int base = blockIdx.x * 8;
    int tid = threadIdx.x;
    if (tid < 8) rdeg[tid] = 1.0f / fmaxf((float)degi[base + tid], 1.0f);
    for (int n = 0; n < 8; ++n) {
        int node = base + n;
        int e0 = off[node], e1 = off[node + 1];
        if (tid < 64) {
            float ax0 = 0, ay0 = 0, ax1 = 0, ay1 = 0;
            float ax2 = 0, ay2 = 0, ax3 = 0, ay3 = 0;
            int e = e0;
            for (; e + 4 <= e1; e += 4) {
                unsigned u0 = pbu[(size_t)csr[e] * 64 + tid];
                unsigned u1 = pbu[(size_t)csr[e + 1] * 64 + tid];
                unsigned u2 = pbu[(size_t)csr[e + 2] * 64 + tid];
                unsigned u3 = pbu[(size_t)csr[e + 3] * 64 + tid];
                ax0 += __uint_as_float(u0 << 16);
                ay0 += __uint_as_float(u0 & 0xffff0000u);
                ax1 += __uint_as_float(u1 << 16);
                ay1 += __uint_as_float(u1 & 0xffff0000u);
                ax2 += __uint_as_float(u2 << 16);
                ay2 += __uint_as_float(u2 & 0xffff0000u);
                ax3 += __uint_as_float(u3 << 16);
                ay3 += __uint_as_float(u3 & 0xffff0000u);
            }
            for (; e < e1; ++e) {
                unsigned u0 = pbu[(size_t)csr[e] * 64 + tid];
                ax0 += __uint_as_float(u0 << 16);
                ay0 += __uint_as_float(u0 & 0xffff0000u);
            }
            mp[n][2 * tid] = (ax0 + ax1) + (ax2 + ax3);
            mp[n][2 * tid + 1] = (ay0 + ay1) + (ay2 + ay3);
        }
    }
    __syncthreads();

    int j = tid;
    float bj = (j < NCLS) ? b2[j] : 0.0f;
    float blj = (j < NCLS) ? bl2[j] : 0.0f;
    float out2[8];
#pragma unroll
    for (int n = 0; n < 8; ++n) {
        out2[n] = (j < NCLS)
                      ? (mp[n][j] * rdeg[n] + bj +
                         __bfloat162float(qrb[(size_t)(base + n) * PSTR + j]))
                      : 0.0f;
        red[n][j] = out2[n] * out2[n];
    }
    __syncthreads();
    for (int stride = 64; stride > 0; stride >>= 1) {
        if (j < stride) {
#pragma unroll
            for (int n = 0; n < 8; ++n) red[n][j] += red[n][j + stride];
        }
        __syncthreads();
    }
    if (j < NCLS) {
#pragma unroll
        for (int n = 0; n < 8; ++n) {
            float rn = 1.0f / fmaxf(sqrtf(red[n][0]), 1e-12f);
            out[(base + n) * NCLS + j] =
                out2[n] * rn +
                __bfloat162float(qlb[(size_t)(base + n) * PSTR + j]) + blj;
        }
    }
}

extern "C" void kernel_launch(void* const* d_in, const int* in_sizes, int n_in,
                              void* d_out, int out_size, void* d_ws, size_t ws_size,
                              hipStream_t stream) {
    const float* x   = (const float*)d_in[0];
    const int*   ei  = (const int*)d_in[1];
    const float* w1l = (const float*)d_in[2];
    const float* b1  = (const float*)d_in[3];
    const float* w1r = (const float*)d_in[4];
    const float* wl1 = (const float*)d_in[5];
    const float* bl1 = (const float*)d_in[6];
    const float* w2l = (const float*)d_in[7];
    const float* b2  = (const float*)d_in[8];
    const float* w2r = (const float*)d_in[9];
    const float* wl2 = (const float*)d_in[10];
    const float* bl2 = (const float*)d_in[11];
    float* out = (float*)d_out;

    const int* src = ei;
    const int* dst = ei + N_EDGES;

    int*   wsI   = (int*)d_ws;
    float* wsF   = (float*)d_ws;
    int*   degi  = wsI;
    int*   off   = wsI + OFF_OFF;
    int*   cur   = wsI + OFF_CUR;
    int*   csr   = wsI + OFF_CSR;
    bf16*  hb    = (bf16*)(wsF + OFF_HB);
    bf16*  pb    = (bf16*)(wsF + OFF_PB);
    bf16*  ab    = (bf16*)(wsF + OFF_AB);
    bf16*  xb    = (bf16*)(wsF + OFF_XB);
    bf16*  qrb   = (bf16*)(wsF + OFF_QRB);
    bf16*  qlb   = (bf16*)(wsF + OFF_QLB);
    bf16*  bw    = (bf16*)(wsF + OFF_BW);
    bf16*  bw1   = (bf16*)(wsF + OFF_BW1);
    int*   csum  = wsI + OFF_CSUM;
    int*   cbase = wsI + OFF_CBASE;

    hipMemsetAsync(degi, 0, (size_t)N_NODES * sizeof(int), stream);

    convx_r17<<<(N_NODES * 128 + 255) / 256, 256, 0, stream>>>(x, xb, ab);
    packw1_r17<<<(4 * 512 * 32 + 255) / 256, 256, 0, stream>>>(w1l, w1r, wl1, bw1);
    packw2_r17<<<(8 * 384 * 32 + 255) / 256, 256, 0, stream>>>(w2l, w2r, wl2, bw);
    degcount_r17<<<(N_EDGES + 255) / 256, 256, 0, stream>>>(dst, degi);

    // 3-phase parallel exclusive scan (replaces 121 us single-block scan)
    chunksum_r17<<<NCHUNK, 256, 0, stream>>>(degi, csum);
    scanchunks_r17<<<1, 256, 0, stream>>>(csum, cbase, off);
    scatteroff_r17<<<NCHUNK, 256, 0, stream>>>(degi, cbase, off, cur);

    csrfill_r17<<<(N_EDGES + 255) / 256, 256, 0, stream>>>(src, dst, cur, csr);

    gather1_r17<<<N_NODES / 8, 256, 0, stream>>>((const unsigned int*)xb, off,
                                                 csr, degi, (unsigned int*)ab);
    proj1_r17<<<N_NODES / 16, 256, 0, stream>>>(ab, bw1, b1, bl1, hb);
    proj2_r17<<<N_NODES / 16, 256, 0, stream>>>(hb, bw, pb, qrb, qlb);
    final_r17<<<N_NODES / 8, 128, 0, stream>>>((const unsigned int*)pb, qrb, qlb,
                                               off, csr, degi, b2, bl2, out);
}